// Round 2
// baseline (3172.975 us; speedup 1.0000x reference)
//
#include <hip/hip_runtime.h>
#include <hip/hip_bf16.h>

// ---------------- CSR build ----------------

__global__ __launch_bounds__(256) void k_count(const int* __restrict__ dst,
                                               int* __restrict__ cnt, int n) {
    int e = blockIdx.x * 256 + threadIdx.x;
    if (e < n) atomicAdd(&cnt[dst[e]], 1);
}

// block-wise exclusive scan (within-block), block totals to bsum
__global__ __launch_bounds__(1024) void k_scan1(const int* __restrict__ cnt,
                                                int* __restrict__ rowst,
                                                int* __restrict__ bsum, int n) {
    __shared__ int tmp[1024];
    int t = threadIdx.x;
    int i = blockIdx.x * 1024 + t;
    int v = (i < n) ? cnt[i] : 0;
    tmp[t] = v;
    __syncthreads();
    for (int off = 1; off < 1024; off <<= 1) {
        int u = 0;
        if (t >= off) u = tmp[t - off];
        __syncthreads();
        if (t >= off) tmp[t] += u;
        __syncthreads();
    }
    if (i < n) rowst[i] = tmp[t] - v;  // exclusive within block
    if (t == 1023) bsum[blockIdx.x] = tmp[1023];
}

__global__ void k_scan2(int* bsum, int nb, int* rowst, int n) {
    if (threadIdx.x == 0 && blockIdx.x == 0) {
        int c = 0;
        for (int i = 0; i < nb; ++i) { int v = bsum[i]; bsum[i] = c; c += v; }
        rowst[n] = c;
    }
}

__global__ __launch_bounds__(256) void k_scan3(const int* __restrict__ cnt,
                                               int* __restrict__ rowst,
                                               const int* __restrict__ bsum,
                                               int* __restrict__ cur,
                                               float* __restrict__ inv, int n) {
    int i = blockIdx.x * 256 + threadIdx.x;
    if (i < n) {
        int r = rowst[i] + bsum[i >> 10];
        rowst[i] = r;
        cur[i] = r;
        int c = cnt[i];
        inv[i] = 1.0f / (float)(c > 1 ? c : 1);
    }
}

__global__ __launch_bounds__(256) void k_scatter(const int* __restrict__ src,
                                                 const int* __restrict__ dst,
                                                 int* __restrict__ cur,
                                                 int* __restrict__ ssrc, int n) {
    int e = blockIdx.x * 256 + threadIdx.x;
    if (e < n) {
        int d = dst[e];
        int p = atomicAdd(&cur[d], 1);
        ssrc[p] = src[e];
    }
}

// ---------------- mean aggregation over CSR ----------------
// 8 nodes per 256-thread block; 32-lane group per node; lanes 0..24 hold float4
__global__ __launch_bounds__(256) void k_aggr(const float* __restrict__ X,
                                              const int* __restrict__ ssrc,
                                              const int* __restrict__ rowst,
                                              const float* __restrict__ inv,
                                              float* __restrict__ out, int n) {
    int g = threadIdx.x >> 5;
    int l = threadIdx.x & 31;
    int node = blockIdx.x * 8 + g;
    if (node >= n) return;
    int s = rowst[node];
    int e = rowst[node + 1];
    bool act = l < 25;
    float ax = 0.f, ay = 0.f, az = 0.f, aw = 0.f;
    int i = s;
    for (; i + 4 <= e; i += 4) {
        int s0 = ssrc[i], s1 = ssrc[i + 1], s2 = ssrc[i + 2], s3 = ssrc[i + 3];
        if (act) {
            float4 v0 = *(const float4*)&X[(size_t)s0 * 100 + l * 4];
            float4 v1 = *(const float4*)&X[(size_t)s1 * 100 + l * 4];
            float4 v2 = *(const float4*)&X[(size_t)s2 * 100 + l * 4];
            float4 v3 = *(const float4*)&X[(size_t)s3 * 100 + l * 4];
            ax += v0.x + v1.x + v2.x + v3.x;
            ay += v0.y + v1.y + v2.y + v3.y;
            az += v0.z + v1.z + v2.z + v3.z;
            aw += v0.w + v1.w + v2.w + v3.w;
        }
    }
    for (; i < e; ++i) {
        int s0 = ssrc[i];
        if (act) {
            float4 v0 = *(const float4*)&X[(size_t)s0 * 100 + l * 4];
            ax += v0.x; ay += v0.y; az += v0.z; aw += v0.w;
        }
    }
    if (act) {
        float f = inv[node];
        float4 o; o.x = ax * f; o.y = ay * f; o.z = az * f; o.w = aw * f;
        *(float4*)&out[(size_t)node * 100 + l * 4] = o;
    }
}

// ---------------- fused double-GEMM: out = act(A@Wl + X@Wr + b) ----------------
// Weight-stationary in VGPRs. Lane <-> output column: global wave pair
// (gw>>1) owns 8-row groups; half (gw&1) selects cols 0..63 / 64..99.
// Each lane holds its private W columns: wl[100] + wr[100] = 200 VGPRs.
// Row addresses are wave-uniform (readfirstlane) -> broadcast/scalar loads.
// No LDS, no __syncthreads, no bank conflicts. In-place out==A is safe:
// each row is fully read (into acc) before it is written, and rows are
// partitioned across wave-pairs.
#define GROWS 8
__global__ __launch_bounds__(256, 2) void k_gemm(const float* __restrict__ X,
                                                 const float* __restrict__ A,
                                                 const float* __restrict__ Wl,
                                                 const float* __restrict__ Wr,
                                                 const float* __restrict__ bias,
                                                 float* __restrict__ out,
                                                 int relu, int n) {
    const int tid = threadIdx.x;
    const int lane = tid & 63;
    const int wave = __builtin_amdgcn_readfirstlane(tid >> 6);
    const int gw = blockIdx.x * 4 + wave;
    const int pair = gw >> 1;
    const int half = gw & 1;
    const int npairs = gridDim.x * 2;
    const int c = lane + half * 64;   // 0..127
    const bool cv = (c < 100);
    const int cs = cv ? c : 99;       // clamp for safe loads

    float wl[100], wr[100];
#pragma unroll
    for (int k = 0; k < 100; ++k) {
        wl[k] = Wl[k * 100 + cs];
        wr[k] = Wr[k * 100 + cs];
    }
    const float bb = bias[cs];

    const int ngroups = (n + GROWS - 1) / GROWS;
    for (int g = pair; g < ngroups; g += npairs) {
        const int r0 = __builtin_amdgcn_readfirstlane(g * GROWS);
        float acc[GROWS];
#pragma unroll
        for (int r = 0; r < GROWS; ++r) acc[r] = bb;

        if (r0 + GROWS <= n) {
#pragma unroll
            for (int k4 = 0; k4 < 25; ++k4) {
#pragma unroll
                for (int r = 0; r < GROWS; ++r) {
                    const float4 av = *(const float4*)(A + (size_t)(r0 + r) * 100 + k4 * 4);
                    const float4 xv = *(const float4*)(X + (size_t)(r0 + r) * 100 + k4 * 4);
                    acc[r] += av.x * wl[k4 * 4 + 0] + av.y * wl[k4 * 4 + 1]
                            + av.z * wl[k4 * 4 + 2] + av.w * wl[k4 * 4 + 3]
                            + xv.x * wr[k4 * 4 + 0] + xv.y * wr[k4 * 4 + 1]
                            + xv.z * wr[k4 * 4 + 2] + xv.w * wr[k4 * 4 + 3];
                }
            }
        } else {
#pragma unroll
            for (int k4 = 0; k4 < 25; ++k4) {
#pragma unroll
                for (int r = 0; r < GROWS; ++r) {
                    if (r0 + r < n) {
                        const float4 av = *(const float4*)(A + (size_t)(r0 + r) * 100 + k4 * 4);
                        const float4 xv = *(const float4*)(X + (size_t)(r0 + r) * 100 + k4 * 4);
                        acc[r] += av.x * wl[k4 * 4 + 0] + av.y * wl[k4 * 4 + 1]
                                + av.z * wl[k4 * 4 + 2] + av.w * wl[k4 * 4 + 3]
                                + xv.x * wr[k4 * 4 + 0] + xv.y * wr[k4 * 4 + 1]
                                + xv.z * wr[k4 * 4 + 2] + xv.w * wr[k4 * 4 + 3];
                    }
                }
            }
        }

        if (cv) {
#pragma unroll
            for (int r = 0; r < GROWS; ++r) {
                if (r0 + r < n) {
                    float v = acc[r];
                    if (relu) v = fmaxf(v, 0.f);
                    out[(size_t)(r0 + r) * 100 + c] = v;
                }
            }
        }
    }
}

// ---------------- global mean pool + linear head ----------------
// batch is sorted: block g binary-searches its node range.
__global__ __launch_bounds__(128) void k_pool(const float* __restrict__ H,
                                              const int* __restrict__ batch,
                                              const float* __restrict__ Wlin,
                                              const float* __restrict__ blin,
                                              float* __restrict__ out, int n) {
    int g = blockIdx.x;
    int t = threadIdx.x;
    int lo = 0, hi = n;
    while (lo < hi) { int m = (lo + hi) >> 1; if (batch[m] < g) lo = m + 1; else hi = m; }
    int lo2 = lo, hi2 = n;
    while (lo2 < hi2) { int m = (lo2 + hi2) >> 1; if (batch[m] < g + 1) lo2 = m + 1; else hi2 = m; }

    __shared__ float gm[100];
    float acc = 0.f;
    if (t < 100) {
        int i = lo;
        for (; i + 2 <= lo2; i += 2)
            acc += H[(size_t)i * 100 + t] + H[(size_t)(i + 1) * 100 + t];
        if (i < lo2) acc += H[(size_t)i * 100 + t];
        float f = (lo2 > lo) ? 1.0f / (float)(lo2 - lo) : 0.0f;
        gm[t] = acc * f;
    }
    __syncthreads();
    if (t < 2) {
        float o = blin[t];
        for (int k = 0; k < 100; ++k) o += gm[k] * Wlin[k * 2 + t];
        out[g * 2 + t] = o;
    }
}

// ---------------- launch ----------------

extern "C" void kernel_launch(void* const* d_in, const int* in_sizes, int n_in,
                              void* d_out, int out_size, void* d_ws, size_t ws_size,
                              hipStream_t stream) {
    const float* x    = (const float*)d_in[0];
    const int*   ei   = (const int*)d_in[1];
    const int*   batch= (const int*)d_in[2];
    const float* W1l  = (const float*)d_in[3];
    const float* b1   = (const float*)d_in[4];
    const float* W1r  = (const float*)d_in[5];
    const float* W2l  = (const float*)d_in[6];
    const float* b2   = (const float*)d_in[7];
    const float* W2r  = (const float*)d_in[8];
    const float* W3l  = (const float*)d_in[9];
    const float* b3   = (const float*)d_in[10];
    const float* W3r  = (const float*)d_in[11];
    const float* Wlin = (const float*)d_in[12];
    const float* blin = (const float*)d_in[13];
    float* out = (float*)d_out;

    const int n_nodes  = in_sizes[0] / 100;
    const int n_edges  = in_sizes[1] / 2;
    const int n_graphs = out_size / 2;
    const int* src = ei;
    const int* dst = ei + n_edges;

    char* ws = (char*)d_ws;
    size_t o = 0;
    auto alloc = [&](size_t bytes) { size_t r = o; o = (o + bytes + 255) & ~(size_t)255; return r; };
    int*   cnt  = (int*)(ws + alloc((size_t)n_nodes * 4));
    int*   rowp = (int*)(ws + alloc((size_t)(n_nodes + 1) * 4));
    int*   cur  = (int*)(ws + alloc((size_t)n_nodes * 4));
    int*   bsum = (int*)(ws + alloc(64 * 4));
    float* inv  = (float*)(ws + alloc((size_t)n_nodes * 4));
    int*   ssrc = (int*)(ws + alloc((size_t)n_edges * 4));
    float* A    = (float*)(ws + alloc((size_t)n_nodes * 100 * 4));
    float* B    = (float*)(ws + alloc((size_t)n_nodes * 100 * 4));

    hipMemsetAsync(cnt, 0, (size_t)n_nodes * 4, stream);

    const int eb = (n_edges + 255) / 256;
    const int sb = (n_nodes + 1023) / 1024;
    k_count<<<eb, 256, 0, stream>>>(dst, cnt, n_edges);
    k_scan1<<<sb, 1024, 0, stream>>>(cnt, rowp, bsum, n_nodes);
    k_scan2<<<1, 64, 0, stream>>>(bsum, sb, rowp, n_nodes);
    k_scan3<<<(n_nodes + 255) / 256, 256, 0, stream>>>(cnt, rowp, bsum, cur, inv, n_nodes);
    k_scatter<<<eb, 256, 0, stream>>>(src, dst, cur, ssrc, n_edges);

    const int ab = (n_nodes + 7) / 8;
    const int GB = 512;  // 2048 waves = 1024 col-pairs, grid-stride over 6250 groups

    // layer 1: A = aggr(x); A = relu(A@W1l + x@W1r + b1)
    k_aggr<<<ab, 256, 0, stream>>>(x, ssrc, rowp, inv, A, n_nodes);
    k_gemm<<<GB, 256, 0, stream>>>(x, A, W1l, W1r, b1, A, 1, n_nodes);
    // layer 2
    k_aggr<<<ab, 256, 0, stream>>>(A, ssrc, rowp, inv, B, n_nodes);
    k_gemm<<<GB, 256, 0, stream>>>(A, B, W2l, W2r, b2, B, 1, n_nodes);
    // layer 3 (no relu)
    k_aggr<<<ab, 256, 0, stream>>>(B, ssrc, rowp, inv, A, n_nodes);
    k_gemm<<<GB, 256, 0, stream>>>(B, A, W3l, W3r, b3, A, 0, n_nodes);

    k_pool<<<n_graphs, 128, 0, stream>>>(A, batch, Wlin, blin, out, n_nodes);
}

// Round 3
// 508.829 us; speedup vs baseline: 6.2358x; 6.2358x over previous
//
#include <hip/hip_runtime.h>
#include <hip/hip_bf16.h>

typedef __attribute__((ext_vector_type(8))) short short8v;
typedef __attribute__((ext_vector_type(4))) float f32x4;

#define USTRIDE 224  // K = 100 (aggr) + 100 (x) + 24 zero pad

static __device__ inline unsigned short f2bf(float x) {
    union { float f; unsigned int u; } c; c.f = x;
    unsigned int r = (c.u + 0x7FFFu + ((c.u >> 16) & 1u)) >> 16;
    return (unsigned short)r;
}
static __device__ inline float bf2f(unsigned short h) {
    union { float f; unsigned int u; } c; c.u = ((unsigned int)h) << 16;
    return c.f;
}
static __device__ inline f32x4 MF(short8v a, short8v b, f32x4 c) {
    return __builtin_amdgcn_mfma_f32_16x16x32_bf16(a, b, c, 0, 0, 0);
}

// ---------------- CSR build ----------------

__global__ __launch_bounds__(256) void k_count(const int* __restrict__ dst,
                                               int* __restrict__ cnt, int n) {
    int e = blockIdx.x * 256 + threadIdx.x;
    if (e < n) atomicAdd(&cnt[dst[e]], 1);
}

__global__ __launch_bounds__(1024) void k_scan1(const int* __restrict__ cnt,
                                                int* __restrict__ rowst,
                                                int* __restrict__ bsum, int n) {
    __shared__ int tmp[1024];
    int t = threadIdx.x;
    int i = blockIdx.x * 1024 + t;
    int v = (i < n) ? cnt[i] : 0;
    tmp[t] = v;
    __syncthreads();
    for (int off = 1; off < 1024; off <<= 1) {
        int u = 0;
        if (t >= off) u = tmp[t - off];
        __syncthreads();
        if (t >= off) tmp[t] += u;
        __syncthreads();
    }
    if (i < n) rowst[i] = tmp[t] - v;
    if (t == 1023) bsum[blockIdx.x] = tmp[1023];
}

__global__ void k_scan2(int* bsum, int nb, int* rowst, int n) {
    if (threadIdx.x == 0 && blockIdx.x == 0) {
        int c = 0;
        for (int i = 0; i < nb; ++i) { int v = bsum[i]; bsum[i] = c; c += v; }
        rowst[n] = c;
    }
}

__global__ __launch_bounds__(256) void k_scan3(const int* __restrict__ cnt,
                                               int* __restrict__ rowst,
                                               const int* __restrict__ bsum,
                                               int* __restrict__ cur,
                                               float* __restrict__ inv, int n) {
    int i = blockIdx.x * 256 + threadIdx.x;
    if (i < n) {
        int r = rowst[i] + bsum[i >> 10];
        rowst[i] = r;
        cur[i] = r;
        int c = cnt[i];
        inv[i] = 1.0f / (float)(c > 1 ? c : 1);
    }
}

__global__ __launch_bounds__(256) void k_scatter(const int* __restrict__ src,
                                                 const int* __restrict__ dst,
                                                 int* __restrict__ cur,
                                                 int* __restrict__ ssrc, int n) {
    int e = blockIdx.x * 256 + threadIdx.x;
    if (e < n) {
        int d = dst[e];
        int p = atomicAdd(&cur[d], 1);
        ssrc[p] = src[e];
    }
}

// ---------------- x -> bf16 pair conversion into U.x-slot ----------------
__global__ __launch_bounds__(256) void k_cvt(const float* __restrict__ X,
                                             unsigned short* __restrict__ Uhi,
                                             unsigned short* __restrict__ Ulo,
                                             int n) {
    int g = threadIdx.x >> 5, l = threadIdx.x & 31;
    int i = blockIdx.x * 8 + g;
    if (i >= n || l >= 25) return;
    float4 v = *(const float4*)(X + (size_t)i * 100 + l * 4);
    size_t o = (size_t)i * USTRIDE + 100 + l * 4;
    ushort4 h, lo;
    h.x = f2bf(v.x); lo.x = f2bf(v.x - bf2f(h.x));
    h.y = f2bf(v.y); lo.y = f2bf(v.y - bf2f(h.y));
    h.z = f2bf(v.z); lo.z = f2bf(v.z - bf2f(h.z));
    h.w = f2bf(v.w); lo.w = f2bf(v.w - bf2f(h.w));
    *(ushort4*)(Uhi + o) = h;
    *(ushort4*)(Ulo + o) = lo;
}

// ---------------- mean aggregation over CSR (bf16-pair in, pair out) --------
// 8 nodes/block; 32-lane group per node; lanes 0..24: 4 feats each.
// Reads x-slot (offset 100) of U, writes aggr-slot (offset 0) + zero pad.
__global__ __launch_bounds__(256) void k_aggr(const unsigned short* __restrict__ Xhi,
                                              const unsigned short* __restrict__ Xlo,
                                              const int* __restrict__ ssrc,
                                              const int* __restrict__ rowst,
                                              const float* __restrict__ inv,
                                              unsigned short* __restrict__ Ohi,
                                              unsigned short* __restrict__ Olo,
                                              int n) {
    int g = threadIdx.x >> 5;
    int l = threadIdx.x & 31;
    int node = blockIdx.x * 8 + g;
    if (node >= n) return;
    size_t obase = (size_t)node * USTRIDE;
    // zero the K pad (elements 200..223) with lanes 25..30
    if (l >= 25 && l <= 30) {
        ushort4 z; z.x = z.y = z.z = z.w = 0;
        size_t po = obase + 200 + (l - 25) * 4;
        *(ushort4*)(Ohi + po) = z;
        *(ushort4*)(Olo + po) = z;
    }
    int s = rowst[node];
    int e = rowst[node + 1];
    bool act = l < 25;
    float a0 = 0.f, a1 = 0.f, a2 = 0.f, a3 = 0.f;
    int i = s;
    for (; i + 2 <= e; i += 2) {
        int s0 = ssrc[i], s1 = ssrc[i + 1];
        if (act) {
            size_t o0 = (size_t)s0 * USTRIDE + 100 + l * 4;
            size_t o1 = (size_t)s1 * USTRIDE + 100 + l * 4;
            ushort4 h0 = *(const ushort4*)(Xhi + o0);
            ushort4 l0 = *(const ushort4*)(Xlo + o0);
            ushort4 h1 = *(const ushort4*)(Xhi + o1);
            ushort4 l1 = *(const ushort4*)(Xlo + o1);
            a0 += bf2f(h0.x) + bf2f(l0.x) + bf2f(h1.x) + bf2f(l1.x);
            a1 += bf2f(h0.y) + bf2f(l0.y) + bf2f(h1.y) + bf2f(l1.y);
            a2 += bf2f(h0.z) + bf2f(l0.z) + bf2f(h1.z) + bf2f(l1.z);
            a3 += bf2f(h0.w) + bf2f(l0.w) + bf2f(h1.w) + bf2f(l1.w);
        }
    }
    for (; i < e; ++i) {
        int s0 = ssrc[i];
        if (act) {
            size_t o0 = (size_t)s0 * USTRIDE + 100 + l * 4;
            ushort4 h0 = *(const ushort4*)(Xhi + o0);
            ushort4 l0 = *(const ushort4*)(Xlo + o0);
            a0 += bf2f(h0.x) + bf2f(l0.x);
            a1 += bf2f(h0.y) + bf2f(l0.y);
            a2 += bf2f(h0.z) + bf2f(l0.z);
            a3 += bf2f(h0.w) + bf2f(l0.w);
        }
    }
    if (act) {
        float f = inv[node];
        a0 *= f; a1 *= f; a2 *= f; a3 *= f;
        ushort4 h, lo;
        h.x = f2bf(a0); lo.x = f2bf(a0 - bf2f(h.x));
        h.y = f2bf(a1); lo.y = f2bf(a1 - bf2f(h.y));
        h.z = f2bf(a2); lo.z = f2bf(a2 - bf2f(h.z));
        h.w = f2bf(a3); lo.w = f2bf(a3 - bf2f(h.w));
        size_t o = obase + l * 4;
        *(ushort4*)(Ohi + o) = h;
        *(ushort4*)(Olo + o) = lo;
    }
}

// ---------------- weight pack: Wcat[224][112] -> B-fragment order -----------
// frag element (lane, j) of tile (kc, nt): k = kc*32 + (lane>>4)*8 + j,
// c = nt*16 + (lane&15). Stored hi/lo at [((kc*7+nt)*64 + lane)*8 + j].
__global__ __launch_bounds__(256) void k_pack(const float* __restrict__ Wl,
                                              const float* __restrict__ Wr,
                                              unsigned short* __restrict__ Bph,
                                              unsigned short* __restrict__ Bpl) {
    int idx = blockIdx.x * 256 + threadIdx.x;
    if (idx >= 7 * 7 * 64) return;
    int lane = idx & 63;
    int t = idx >> 6;
    int nt = t % 7;
    int kc = t / 7;
    int c = nt * 16 + (lane & 15);
    int kbase = kc * 32 + (lane >> 4) * 8;
    for (int j = 0; j < 8; ++j) {
        int k = kbase + j;
        float w = 0.f;
        if (c < 100) {
            if (k < 100) w = Wl[k * 100 + c];
            else if (k < 200) w = Wr[(k - 100) * 100 + c];
        }
        unsigned short h = f2bf(w);
        unsigned short lo = f2bf(w - bf2f(h));
        Bph[(size_t)idx * 8 + j] = h;
        Bpl[(size_t)idx * 8 + j] = lo;
    }
}

// ---------------- MFMA GEMM: O.x-slot = act(U @ Wcat + b) -------------------
// 1 wave = 32 rows (2 M-tiles of 16), N=112 (7 tiles), K=224 (7 chunks).
// 3-term bf16 split: hi*hi + hi*lo + lo*hi. No LDS, no barriers.
__global__ __launch_bounds__(256) void k_gemm(const unsigned short* __restrict__ Uhi,
                                              const unsigned short* __restrict__ Ulo,
                                              const unsigned short* __restrict__ Bph,
                                              const unsigned short* __restrict__ Bpl,
                                              const float* __restrict__ bias,
                                              unsigned short* __restrict__ Ohi,
                                              unsigned short* __restrict__ Olo,
                                              int relu, int n, int ntasks) {
    const int lane = threadIdx.x & 63;
    const int wv = threadIdx.x >> 6;
    const int task = blockIdx.x * 4 + wv;
    if (task >= ntasks) return;
    const int m0 = task * 32;
    const int lrow = lane & 15;
    const int lg = lane >> 4;

    f32x4 acc[2][7];
#pragma unroll
    for (int mt = 0; mt < 2; ++mt)
#pragma unroll
        for (int nt = 0; nt < 7; ++nt) acc[mt][nt] = (f32x4){0.f, 0.f, 0.f, 0.f};

    int r0 = m0 + lrow;      if (r0 >= n) r0 = n - 1;
    int r1 = m0 + 16 + lrow; if (r1 >= n) r1 = n - 1;
    const size_t ub0 = (size_t)r0 * USTRIDE + lg * 8;
    const size_t ub1 = (size_t)r1 * USTRIDE + lg * 8;

#pragma unroll
    for (int kc = 0; kc < 7; ++kc) {
        short8v ah0 = *(const short8v*)(Uhi + ub0 + kc * 32);
        short8v al0 = *(const short8v*)(Ulo + ub0 + kc * 32);
        short8v ah1 = *(const short8v*)(Uhi + ub1 + kc * 32);
        short8v al1 = *(const short8v*)(Ulo + ub1 + kc * 32);
        const unsigned short* bh = Bph + ((size_t)(kc * 7) * 64 + lane) * 8;
        const unsigned short* bl = Bpl + ((size_t)(kc * 7) * 64 + lane) * 8;
#pragma unroll
        for (int nt = 0; nt < 7; ++nt) {
            short8v bhf = *(const short8v*)(bh + nt * 512);
            short8v blf = *(const short8v*)(bl + nt * 512);
            acc[0][nt] = MF(ah0, bhf, acc[0][nt]);
            acc[0][nt] = MF(ah0, blf, acc[0][nt]);
            acc[0][nt] = MF(al0, bhf, acc[0][nt]);
            acc[1][nt] = MF(ah1, bhf, acc[1][nt]);
            acc[1][nt] = MF(ah1, blf, acc[1][nt]);
            acc[1][nt] = MF(al1, bhf, acc[1][nt]);
        }
    }

    // epilogue: C/D layout col=lane&15, row=(lane>>4)*4+reg  [HW-verified]
#pragma unroll
    for (int nt = 0; nt < 7; ++nt) {
        int col = nt * 16 + lrow;
        bool cok = col < 100;
        float bb = cok ? bias[col] : 0.f;
#pragma unroll
        for (int mt = 0; mt < 2; ++mt) {
#pragma unroll
            for (int r = 0; r < 4; ++r) {
                int row = m0 + mt * 16 + lg * 4 + r;
                if (cok && row < n) {
                    float v = acc[mt][nt][r] + bb;
                    if (relu) v = fmaxf(v, 0.f);
                    unsigned short h = f2bf(v);
                    unsigned short lo = f2bf(v - bf2f(h));
                    size_t o = (size_t)row * USTRIDE + 100 + col;
                    Ohi[o] = h;
                    Olo[o] = lo;
                }
            }
        }
    }
}

// ---------------- global mean pool + linear head ----------------
__global__ __launch_bounds__(128) void k_pool(const unsigned short* __restrict__ Hhi,
                                              const unsigned short* __restrict__ Hlo,
                                              const int* __restrict__ batch,
                                              const float* __restrict__ Wlin,
                                              const float* __restrict__ blin,
                                              float* __restrict__ out, int n) {
    int g = blockIdx.x;
    int t = threadIdx.x;
    int lo = 0, hi = n;
    while (lo < hi) { int m = (lo + hi) >> 1; if (batch[m] < g) lo = m + 1; else hi = m; }
    int lo2 = lo, hi2 = n;
    while (lo2 < hi2) { int m = (lo2 + hi2) >> 1; if (batch[m] < g + 1) lo2 = m + 1; else hi2 = m; }

    __shared__ float gm[100];
    if (t < 100) {
        float acc = 0.f;
        for (int i = lo; i < lo2; ++i) {
            size_t o = (size_t)i * USTRIDE + 100 + t;
            acc += bf2f(Hhi[o]) + bf2f(Hlo[o]);
        }
        float f = (lo2 > lo) ? 1.0f / (float)(lo2 - lo) : 0.0f;
        gm[t] = acc * f;
    }
    __syncthreads();
    if (t < 2) {
        float o = blin[t];
        for (int k = 0; k < 100; ++k) o += gm[k] * Wlin[k * 2 + t];
        out[g * 2 + t] = o;
    }
}

// ---------------- launch ----------------

extern "C" void kernel_launch(void* const* d_in, const int* in_sizes, int n_in,
                              void* d_out, int out_size, void* d_ws, size_t ws_size,
                              hipStream_t stream) {
    const float* x    = (const float*)d_in[0];
    const int*   ei   = (const int*)d_in[1];
    const int*   batch= (const int*)d_in[2];
    const float* W1l  = (const float*)d_in[3];
    const float* b1   = (const float*)d_in[4];
    const float* W1r  = (const float*)d_in[5];
    const float* W2l  = (const float*)d_in[6];
    const float* b2   = (const float*)d_in[7];
    const float* W2r  = (const float*)d_in[8];
    const float* W3l  = (const float*)d_in[9];
    const float* b3   = (const float*)d_in[10];
    const float* W3r  = (const float*)d_in[11];
    const float* Wlin = (const float*)d_in[12];
    const float* blin = (const float*)d_in[13];
    float* out = (float*)d_out;

    const int n_nodes  = in_sizes[0] / 100;
    const int n_edges  = in_sizes[1] / 2;
    const int n_graphs = out_size / 2;
    const int* src = ei;
    const int* dst = ei + n_edges;

    char* ws = (char*)d_ws;
    size_t o = 0;
    auto alloc = [&](size_t bytes) { size_t r = o; o = (o + bytes + 255) & ~(size_t)255; return r; };
    int*   cnt  = (int*)(ws + alloc((size_t)n_nodes * 4));
    int*   rowp = (int*)(ws + alloc((size_t)(n_nodes + 1) * 4));
    int*   cur  = (int*)(ws + alloc((size_t)n_nodes * 4));
    int*   bsum = (int*)(ws + alloc(64 * 4));
    float* inv  = (float*)(ws + alloc((size_t)n_nodes * 4));
    int*   ssrc = (int*)(ws + alloc((size_t)n_edges * 4));
    const size_t ub = (size_t)n_nodes * USTRIDE * 2;  // bytes per bf16 U plane
    unsigned short* UAhi = (unsigned short*)(ws + alloc(ub));
    unsigned short* UAlo = (unsigned short*)(ws + alloc(ub));
    unsigned short* UBhi = (unsigned short*)(ws + alloc(ub));
    unsigned short* UBlo = (unsigned short*)(ws + alloc(ub));
    const size_t pb = (size_t)7 * 7 * 64 * 8 * 2;  // bytes per packed W plane
    unsigned short* P1h = (unsigned short*)(ws + alloc(pb));
    unsigned short* P1l = (unsigned short*)(ws + alloc(pb));
    unsigned short* P2h = (unsigned short*)(ws + alloc(pb));
    unsigned short* P2l = (unsigned short*)(ws + alloc(pb));
    unsigned short* P3h = (unsigned short*)(ws + alloc(pb));
    unsigned short* P3l = (unsigned short*)(ws + alloc(pb));

    hipMemsetAsync(cnt, 0, (size_t)n_nodes * 4, stream);

    const int eb = (n_edges + 255) / 256;
    const int sb = (n_nodes + 1023) / 1024;
    k_count<<<eb, 256, 0, stream>>>(dst, cnt, n_edges);
    k_scan1<<<sb, 1024, 0, stream>>>(cnt, rowp, bsum, n_nodes);
    k_scan2<<<1, 64, 0, stream>>>(bsum, sb, rowp, n_nodes);
    k_scan3<<<(n_nodes + 255) / 256, 256, 0, stream>>>(cnt, rowp, bsum, cur, inv, n_nodes);
    k_scatter<<<eb, 256, 0, stream>>>(src, dst, cur, ssrc, n_edges);

    const int pkb = (7 * 7 * 64 + 255) / 256;
    k_pack<<<pkb, 256, 0, stream>>>(W1l, W1r, P1h, P1l);
    k_pack<<<pkb, 256, 0, stream>>>(W2l, W2r, P2h, P2l);
    k_pack<<<pkb, 256, 0, stream>>>(W3l, W3r, P3h, P3l);

    const int ab = (n_nodes + 7) / 8;
    const int ntasks = (n_nodes + 31) / 32;
    const int ggrid = (ntasks + 3) / 4;

    k_cvt<<<ab, 256, 0, stream>>>(x, UAhi, UAlo, n_nodes);

    // layer 1
    k_aggr<<<ab, 256, 0, stream>>>(UAhi, UAlo, ssrc, rowp, inv, UAhi, UAlo, n_nodes);
    k_gemm<<<ggrid, 256, 0, stream>>>(UAhi, UAlo, P1h, P1l, b1, UBhi, UBlo, 1, n_nodes, ntasks);
    // layer 2
    k_aggr<<<ab, 256, 0, stream>>>(UBhi, UBlo, ssrc, rowp, inv, UBhi, UBlo, n_nodes);
    k_gemm<<<ggrid, 256, 0, stream>>>(UBhi, UBlo, P2h, P2l, b2, UAhi, UAlo, 1, n_nodes, ntasks);
    // layer 3 (no relu)
    k_aggr<<<ab, 256, 0, stream>>>(UAhi, UAlo, ssrc, rowp, inv, UAhi, UAlo, n_nodes);
    k_gemm<<<ggrid, 256, 0, stream>>>(UAhi, UAlo, P3h, P3l, b3, UBhi, UBlo, 0, n_nodes, ntasks);

    k_pool<<<n_graphs, 128, 0, stream>>>(UBhi, UBlo, batch, Wlin, blin, out, n_nodes);
}

// Round 4
// 508.683 us; speedup vs baseline: 6.2376x; 1.0003x over previous
//
#include <hip/hip_runtime.h>
#include <hip/hip_bf16.h>

typedef __attribute__((ext_vector_type(8))) short short8v;
typedef __attribute__((ext_vector_type(4))) float f32x4;

// U row layout (shorts, stride 448 = 896B):
//   groups of 16 shorts (32B): [8 feats hi | 8 feats lo]
//   aggr part: groups 0..12 (feats 0..99; group 12 tail zero), group 13 = zero pad
//   x    part: groups 14..26 (feats 0..99; group 26 tail zero), group 27 = zero pad
#define USH 448
#define XOFF 224

static __device__ inline unsigned short f2bf(float x) {
    union { float f; unsigned int u; } c; c.f = x;
    unsigned int r = (c.u + 0x7FFFu + ((c.u >> 16) & 1u)) >> 16;
    return (unsigned short)r;
}
static __device__ inline float bf2f(unsigned short h) {
    union { float f; unsigned int u; } c; c.u = ((unsigned int)h) << 16;
    return c.f;
}
static __device__ inline f32x4 MF(short8v a, short8v b, f32x4 c) {
    return __builtin_amdgcn_mfma_f32_16x16x32_bf16(a, b, c, 0, 0, 0);
}

// ---------------- CSR build ----------------

__global__ __launch_bounds__(256) void k_count(const int* __restrict__ dst,
                                               int* __restrict__ cnt, int n) {
    int e = blockIdx.x * 256 + threadIdx.x;
    if (e < n) atomicAdd(&cnt[dst[e]], 1);
}

__global__ __launch_bounds__(1024) void k_scan1(const int* __restrict__ cnt,
                                                int* __restrict__ rowst,
                                                int* __restrict__ bsum, int n) {
    __shared__ int tmp[1024];
    int t = threadIdx.x;
    int i = blockIdx.x * 1024 + t;
    int v = (i < n) ? cnt[i] : 0;
    tmp[t] = v;
    __syncthreads();
    for (int off = 1; off < 1024; off <<= 1) {
        int u = 0;
        if (t >= off) u = tmp[t - off];
        __syncthreads();
        if (t >= off) tmp[t] += u;
        __syncthreads();
    }
    if (i < n) rowst[i] = tmp[t] - v;
    if (t == 1023) bsum[blockIdx.x] = tmp[1023];
}

// folds the cross-block prefix (<=49 blocks) and builds cur/inv; sets rowp[n]
__global__ __launch_bounds__(256) void k_scan3(const int* __restrict__ cnt,
                                               int* __restrict__ rowst,
                                               const int* __restrict__ bsum,
                                               int* __restrict__ cur,
                                               float* __restrict__ inv, int n) {
    int i = blockIdx.x * 256 + threadIdx.x;
    if (i < n) {
        int nb = i >> 10;
        int base = 0;
        for (int j = 0; j < nb; ++j) base += bsum[j];
        int r = rowst[i] + base;
        rowst[i] = r;
        cur[i] = r;
        int c = cnt[i];
        inv[i] = 1.0f / (float)(c > 1 ? c : 1);
        if (i == n - 1) rowst[n] = r + c;
    }
}

__global__ __launch_bounds__(256) void k_scatter(const int* __restrict__ src,
                                                 const int* __restrict__ dst,
                                                 int* __restrict__ cur,
                                                 int* __restrict__ ssrc, int n) {
    int e = blockIdx.x * 256 + threadIdx.x;
    if (e < n) {
        int d = dst[e];
        int p = atomicAdd(&cur[d], 1);
        ssrc[p] = src[e];
    }
}

// ---------------- x (fp32) -> interleaved hi/lo into U x-part ----------------
// 8 nodes/block, 32 lanes per node; lane g<13 handles feat group g; lane 13 zeros pad.
__global__ __launch_bounds__(256) void k_cvt(const float* __restrict__ X,
                                             unsigned short* __restrict__ U, int n) {
    int grp = threadIdx.x >> 5, l = threadIdx.x & 31;
    int i = blockIdx.x * 8 + grp;
    if (i >= n) return;
    unsigned short* row = U + (size_t)i * USH;
    if (l < 13) {
        float f[8];
#pragma unroll
        for (int m = 0; m < 8; ++m) {
            int feat = l * 8 + m;
            f[m] = (feat < 100) ? X[(size_t)i * 100 + feat] : 0.f;
        }
        short8v hv, lv;
#pragma unroll
        for (int m = 0; m < 8; ++m) {
            unsigned short h = f2bf(f[m]);
            hv[m] = (short)h;
            lv[m] = (short)f2bf(f[m] - bf2f(h));
        }
        *(short8v*)(row + XOFF + l * 16) = hv;
        *(short8v*)(row + XOFF + l * 16 + 8) = lv;
    } else if (l == 13) {
        short8v z = (short8v){0,0,0,0,0,0,0,0};
        *(short8v*)(row + XOFF + 13 * 16) = z;       // group 27 first half
        *(short8v*)(row + XOFF + 13 * 16 + 8) = z;   // group 27 second half
    }
}

// ---------------- mean aggregation over CSR ----------------
// 8 nodes/block; 32 lanes per node; lanes 0..25 each load 16B of the 416B x-part.
// Even lane j=2g holds hi-half of group g, odd lane lo-half. Pair-reduce via shfl.
__global__ __launch_bounds__(256) void k_aggr(const unsigned short* __restrict__ U,
                                              const int* __restrict__ ssrc,
                                              const int* __restrict__ rowst,
                                              const float* __restrict__ inv,
                                              unsigned short* __restrict__ O, int n) {
    int grp = threadIdx.x >> 5;
    int l = threadIdx.x & 31;
    int node = blockIdx.x * 8 + grp;
    if (node >= n) return;
    unsigned short* orow = O + (size_t)node * USH;
    if (l == 26 || l == 27) {  // zero aggr pad group 13
        short8v z = (short8v){0,0,0,0,0,0,0,0};
        *(short8v*)(orow + 208 + (l - 26) * 8) = z;
    }
    int s = rowst[node];
    int e = rowst[node + 1];
    const bool act = l < 26;
    float a[8];
#pragma unroll
    for (int m = 0; m < 8; ++m) a[m] = 0.f;
    const size_t loff = XOFF + l * 8;

    int i = s;
    for (; i + 4 <= e; i += 4) {
        int s0 = ssrc[i], s1 = ssrc[i + 1], s2 = ssrc[i + 2], s3 = ssrc[i + 3];
        if (act) {
            short8v v0 = *(const short8v*)(U + (size_t)s0 * USH + loff);
            short8v v1 = *(const short8v*)(U + (size_t)s1 * USH + loff);
            short8v v2 = *(const short8v*)(U + (size_t)s2 * USH + loff);
            short8v v3 = *(const short8v*)(U + (size_t)s3 * USH + loff);
#pragma unroll
            for (int m = 0; m < 8; ++m)
                a[m] += bf2f((unsigned short)v0[m]) + bf2f((unsigned short)v1[m])
                      + bf2f((unsigned short)v2[m]) + bf2f((unsigned short)v3[m]);
        }
    }
    for (; i < e; ++i) {
        int s0 = ssrc[i];
        if (act) {
            short8v v0 = *(const short8v*)(U + (size_t)s0 * USH + loff);
#pragma unroll
            for (int m = 0; m < 8; ++m) a[m] += bf2f((unsigned short)v0[m]);
        }
    }

    const float f = inv[node];
    float tot[8];
#pragma unroll
    for (int m = 0; m < 8; ++m) tot[m] = (a[m] + __shfl_xor(a[m], 1)) * f;

    if (act) {
        short8v w;
        if ((l & 1) == 0) {
#pragma unroll
            for (int m = 0; m < 8; ++m) w[m] = (short)f2bf(tot[m]);
        } else {
#pragma unroll
            for (int m = 0; m < 8; ++m) {
                unsigned short h = f2bf(tot[m]);
                w[m] = (short)f2bf(tot[m] - bf2f(h));
            }
        }
        *(short8v*)(orow + (l >> 1) * 16 + (l & 1) * 8) = w;
    }
}

// ---------------- weight pack ----------------
// B13 (terms uhi*whi + ulo*whi): 14 chunks over interleaved axis, whi at both
// hi- and lo-positions. B2 (term uhi*wlo): 7 chunks over hi-halves (groups 4c+lg).
static __device__ inline float wsrc(const float* Wl, const float* Wr,
                                    int G, int jj, int col) {
    if (col >= 100) return 0.f;
    if (G <= 12) { int f = 8 * G + jj; return (f < 100) ? Wl[f * 100 + col] : 0.f; }
    if (G >= 14 && G <= 26) { int f = 8 * (G - 14) + jj; return (f < 100) ? Wr[f * 100 + col] : 0.f; }
    return 0.f;
}

__global__ __launch_bounds__(256) void k_pack(const float* __restrict__ Wl,
                                              const float* __restrict__ Wr,
                                              unsigned short* __restrict__ B13,
                                              unsigned short* __restrict__ B2) {
    int idx = blockIdx.x * 256 + threadIdx.x;
    const int n13 = 14 * 7 * 64;
    const int n2 = 7 * 7 * 64;
    if (idx < n13) {
        int lane = idx & 63;
        int t = idx >> 6;
        int nt = t % 7, cp = t / 7;
        int lg = lane >> 4;
        int col = nt * 16 + (lane & 15);
        int G = 2 * cp + (lg >> 1);
        for (int jj = 0; jj < 8; ++jj) {
            float w = wsrc(Wl, Wr, G, jj, col);
            B13[(size_t)idx * 8 + jj] = f2bf(w);
        }
    } else if (idx < n13 + n2) {
        int j2 = idx - n13;
        int lane = j2 & 63;
        int t = j2 >> 6;
        int nt = t % 7, c = t / 7;
        int lg = lane >> 4;
        int col = nt * 16 + (lane & 15);
        int G = 4 * c + lg;
        for (int jj = 0; jj < 8; ++jj) {
            float w = wsrc(Wl, Wr, G, jj, col);
            unsigned short h = f2bf(w);
            B2[(size_t)j2 * 8 + jj] = f2bf(w - bf2f(h));
        }
    }
}

// ---------------- MFMA GEMM: Out.x-part = act(U @ [Wl;Wr] + b) --------------
// 1 wave = 32 rows (2 M-tiles), N=112 (7 tiles). 14 interleaved chunks (B13)
// + 7 hi-half chunks (B2) = 294 MFMA/wave. No LDS, no barriers.
__global__ __launch_bounds__(256) void k_gemm(const unsigned short* __restrict__ U,
                                              const unsigned short* __restrict__ B13,
                                              const unsigned short* __restrict__ B2,
                                              const float* __restrict__ bias,
                                              unsigned short* __restrict__ Out,
                                              int relu, int n, int ntasks) {
    const int lane = threadIdx.x & 63;
    const int wv = threadIdx.x >> 6;
    const int task = blockIdx.x * 4 + wv;
    if (task >= ntasks) return;
    const int m0 = task * 32;
    const int lrow = lane & 15;
    const int lg = lane >> 4;

    f32x4 acc[2][7];
#pragma unroll
    for (int mt = 0; mt < 2; ++mt)
#pragma unroll
        for (int nt = 0; nt < 7; ++nt) acc[mt][nt] = (f32x4){0.f, 0.f, 0.f, 0.f};

    int r0 = m0 + lrow;      if (r0 >= n) r0 = n - 1;
    int r1 = m0 + 16 + lrow; if (r1 >= n) r1 = n - 1;
    const size_t ub0 = (size_t)r0 * USH + lg * 8;    // interleaved frags
    const size_t ub1 = (size_t)r1 * USH + lg * 8;
    const size_t xb0 = (size_t)r0 * USH + lg * 16;   // hi-half frags
    const size_t xb1 = (size_t)r1 * USH + lg * 16;

#pragma unroll
    for (int c = 0; c < 14; ++c) {
        short8v a0 = *(const short8v*)(U + ub0 + c * 32);
        short8v a1 = *(const short8v*)(U + ub1 + c * 32);
        const unsigned short* bp = B13 + ((size_t)(c * 7) * 64 + lane) * 8;
#pragma unroll
        for (int nt = 0; nt < 7; ++nt) {
            short8v b = *(const short8v*)(bp + nt * 512);
            acc[0][nt] = MF(a0, b, acc[0][nt]);
            acc[1][nt] = MF(a1, b, acc[1][nt]);
        }
    }
#pragma unroll
    for (int c = 0; c < 7; ++c) {
        short8v a0 = *(const short8v*)(U + xb0 + c * 64);
        short8v a1 = *(const short8v*)(U + xb1 + c * 64);
        const unsigned short* bp = B2 + ((size_t)(c * 7) * 64 + lane) * 8;
#pragma unroll
        for (int nt = 0; nt < 7; ++nt) {
            short8v b = *(const short8v*)(bp + nt * 512);
            acc[0][nt] = MF(a0, b, acc[0][nt]);
            acc[1][nt] = MF(a1, b, acc[1][nt]);
        }
    }

    // epilogue: C/D layout col=lane&15, row=(lane>>4)*4+reg  [HW-verified]
#pragma unroll
    for (int nt = 0; nt < 7; ++nt) {
        int col = nt * 16 + lrow;
        bool cok = col < 100;
        float bb = cok ? bias[cok ? col : 0] : 0.f;
        int gsh = (14 + (col >> 3)) * 16 + (col & 7);  // hi short offset in row
#pragma unroll
        for (int mt = 0; mt < 2; ++mt) {
#pragma unroll
            for (int r = 0; r < 4; ++r) {
                int row = m0 + mt * 16 + lg * 4 + r;
                if (cok && row < n) {
                    float v = acc[mt][nt][r] + bb;
                    if (relu) v = fmaxf(v, 0.f);
                    unsigned short h = f2bf(v);
                    unsigned short lo = f2bf(v - bf2f(h));
                    unsigned short* orow = Out + (size_t)row * USH;
                    orow[gsh] = h;
                    orow[gsh + 8] = lo;
                }
            }
        }
    }
    // zero invalid tails: group-26 positions 4..7 (hi [420,424) lo [428,432))
    // and pad group 27 [432,448). 2 lanes per row.
    {
        int row = m0 + (lane >> 1);
        if (row < n) {
            unsigned short* orow = Out + (size_t)row * USH;
            if ((lane & 1) == 0) {
                short4 z4 = {0, 0, 0, 0};
                *(short4*)(orow + 420) = z4;
                *(short4*)(orow + 428) = z4;
            } else {
                short8v z = (short8v){0,0,0,0,0,0,0,0};
                *(short8v*)(orow + 432) = z;
                *(short8v*)(orow + 440) = z;
            }
        }
    }
}

// ---------------- global mean pool + linear head ----------------
__global__ __launch_bounds__(128) void k_pool(const unsigned short* __restrict__ U,
                                              const int* __restrict__ batch,
                                              const float* __restrict__ Wlin,
                                              const float* __restrict__ blin,
                                              float* __restrict__ out, int n) {
    int g = blockIdx.x;
    int t = threadIdx.x;
    int lo = 0, hi = n;
    while (lo < hi) { int m = (lo + hi) >> 1; if (batch[m] < g) lo = m + 1; else hi = m; }
    int lo2 = lo, hi2 = n;
    while (lo2 < hi2) { int m = (lo2 + hi2) >> 1; if (batch[m] < g + 1) lo2 = m + 1; else hi2 = m; }

    __shared__ float gm[100];
    if (t < 100) {
        int off = XOFF + ((t >> 3) * 16) + (t & 7);
        float acc = 0.f;
        for (int i = lo; i < lo2; ++i) {
            const unsigned short* row = U + (size_t)i * USH;
            acc += bf2f(row[off]) + bf2f(row[off + 8]);
        }
        float f = (lo2 > lo) ? 1.0f / (float)(lo2 - lo) : 0.0f;
        gm[t] = acc * f;
    }
    __syncthreads();
    if (t < 2) {
        float o = blin[t];
        for (int k = 0; k < 100; ++k) o += gm[k] * Wlin[k * 2 + t];
        out[g * 2 + t] = o;
    }
}

// ---------------- launch ----------------

extern "C" void kernel_launch(void* const* d_in, const int* in_sizes, int n_in,
                              void* d_out, int out_size, void* d_ws, size_t ws_size,
                              hipStream_t stream) {
    const float* x    = (const float*)d_in[0];
    const int*   ei   = (const int*)d_in[1];
    const int*   batch= (const int*)d_in[2];
    const float* W1l  = (const float*)d_in[3];
    const float* b1   = (const float*)d_in[4];
    const float* W1r  = (const float*)d_in[5];
    const float* W2l  = (const float*)d_in[6];
    const float* b2   = (const float*)d_in[7];
    const float* W2r  = (const float*)d_in[8];
    const float* W3l  = (const float*)d_in[9];
    const float* b3   = (const float*)d_in[10];
    const float* W3r  = (const float*)d_in[11];
    const float* Wlin = (const float*)d_in[12];
    const float* blin = (const float*)d_in[13];
    float* out = (float*)d_out;

    const int n_nodes  = in_sizes[0] / 100;
    const int n_edges  = in_sizes[1] / 2;
    const int n_graphs = out_size / 2;
    const int* src = ei;
    const int* dst = ei + n_edges;

    char* ws = (char*)d_ws;
    size_t o = 0;
    auto alloc = [&](size_t bytes) { size_t r = o; o = (o + bytes + 255) & ~(size_t)255; return r; };
    int*   cnt  = (int*)(ws + alloc((size_t)n_nodes * 4));
    int*   rowp = (int*)(ws + alloc((size_t)(n_nodes + 1) * 4));
    int*   cur  = (int*)(ws + alloc((size_t)n_nodes * 4));
    int*   bsum = (int*)(ws + alloc(64 * 4));
    float* inv  = (float*)(ws + alloc((size_t)n_nodes * 4));
    int*   ssrc = (int*)(ws + alloc((size_t)n_edges * 4));
    const size_t ubytes = (size_t)n_nodes * USH * 2;
    unsigned short* UA = (unsigned short*)(ws + alloc(ubytes));
    unsigned short* UB = (unsigned short*)(ws + alloc(ubytes));
    const size_t b13b = (size_t)14 * 7 * 64 * 8 * 2;
    const size_t b2b  = (size_t)7 * 7 * 64 * 8 * 2;
    unsigned short* P1a = (unsigned short*)(ws + alloc(b13b));
    unsigned short* P1b = (unsigned short*)(ws + alloc(b2b));
    unsigned short* P2a = (unsigned short*)(ws + alloc(b13b));
    unsigned short* P2b = (unsigned short*)(ws + alloc(b2b));
    unsigned short* P3a = (unsigned short*)(ws + alloc(b13b));
    unsigned short* P3b = (unsigned short*)(ws + alloc(b2b));

    hipMemsetAsync(cnt, 0, (size_t)n_nodes * 4, stream);

    const int eb = (n_edges + 255) / 256;
    const int sb = (n_nodes + 1023) / 1024;
    k_count<<<eb, 256, 0, stream>>>(dst, cnt, n_edges);
    k_scan1<<<sb, 1024, 0, stream>>>(cnt, rowp, bsum, n_nodes);
    k_scan3<<<(n_nodes + 255) / 256, 256, 0, stream>>>(cnt, rowp, bsum, cur, inv, n_nodes);
    k_scatter<<<eb, 256, 0, stream>>>(src, dst, cur, ssrc, n_edges);

    const int pkb = (14 * 7 * 64 + 7 * 7 * 64 + 255) / 256;
    k_pack<<<pkb, 256, 0, stream>>>(W1l, W1r, P1a, P1b);
    k_pack<<<pkb, 256, 0, stream>>>(W2l, W2r, P2a, P2b);
    k_pack<<<pkb, 256, 0, stream>>>(W3l, W3r, P3a, P3b);

    const int ab = (n_nodes + 7) / 8;
    const int ntasks = (n_nodes + 31) / 32;
    const int ggrid = (ntasks + 3) / 4;

    k_cvt<<<ab, 256, 0, stream>>>(x, UA, n_nodes);

    // layer 1: UA.aggr = mean(UA.x); UB.x = relu(UA @ [W1l;W1r] + b1)
    k_aggr<<<ab, 256, 0, stream>>>(UA, ssrc, rowp, inv, UA, n_nodes);
    k_gemm<<<ggrid, 256, 0, stream>>>(UA, P1a, P1b, b1, UB, 1, n_nodes, ntasks);
    // layer 2
    k_aggr<<<ab, 256, 0, stream>>>(UB, ssrc, rowp, inv, UB, n_nodes);
    k_gemm<<<ggrid, 256, 0, stream>>>(UB, P2a, P2b, b2, UA, 1, n_nodes, ntasks);
    // layer 3 (no relu)
    k_aggr<<<ab, 256, 0, stream>>>(UA, ssrc, rowp, inv, UA, n_nodes);
    k_gemm<<<ggrid, 256, 0, stream>>>(UA, P3a, P3b, b3, UB, 0, n_nodes, ntasks);

    k_pool<<<n_graphs, 128, 0, stream>>>(UB, batch, Wlin, blin, out, n_nodes);
}